// Round 4
// baseline (123.581 us; speedup 1.0000x reference)
//
#include <hip/hip_runtime.h>
#include <math.h>

#define B_  32
#define C_  256
#define H_  64
#define W_  64
#define HW  (H_*W_)          // 4096
#define HW4 (HW/4)           // 1024
#define PF_RPB 8             // channel rows per block in pf kernel
#define GD_RPB 16            // channel rows per block in guided kernel

typedef float f32x4 __attribute__((ext_vector_type(4)));

__device__ __forceinline__ float clamp01(float v) {
    return fminf(fmaxf(v, 0.0f), 1.0f);
}

// Kernel A: 4 blocks per batch. boxes -> analytic mask -> conv1(3x3,16)+relu
// -> conv2(1x1)+sigmoid -> refined_mask out + partial area to ws.
__global__ __launch_bounds__(256) void kern_mask(
    const float* __restrict__ xywh,
    const float* __restrict__ conv1_w, const float* __restrict__ conv1_b,
    const float* __restrict__ conv2_w, const float* __restrict__ conv2_b,
    float* __restrict__ out_boxes, float* __restrict__ out_rm,
    float* __restrict__ ws_part)
{
    const int b = blockIdx.x >> 2;
    const int q = blockIdx.x & 3;
    const int t = threadIdx.x;

    __shared__ float sw1[16 * 9];
    __shared__ float sb1[16];
    __shared__ float sw2[16];
    __shared__ float sred[4];

    if (t < 144)                 sw1[t]       = conv1_w[t];
    else if (t < 160)            sb1[t - 144] = conv1_b[t - 144];
    else if (t < 176)            sw2[t - 160] = conv2_w[t - 160];
    const float b2v = conv2_b[0];

    const float xc = xywh[b * 4 + 0];
    const float yc = xywh[b * 4 + 1];
    const float bw = xywh[b * 4 + 2];
    const float bh = xywh[b * 4 + 3];

    float x1 = clamp01(xc - bw * 0.5f);
    float y1 = clamp01(yc - bh * 0.5f);
    float x2 = clamp01(xc + bw * 0.5f);
    float y2 = clamp01(yc + bh * 0.5f);
    float xl = fminf(x1, x2), xh = fmaxf(x1, x2);
    float yl = fminf(y1, y2), yh = fmaxf(y1, y2);
    float w_ = fmaxf(xh - xl, 1e-6f);
    float h_ = fmaxf(yh - yl, 1e-6f);
    float cx = (xh + xl) * 0.5f, cy = (yh + yl) * 0.5f;
    float bx1 = clamp01(cx - w_ * 0.5f);
    float by1 = clamp01(cy - h_ * 0.5f);
    float bx2 = clamp01(cx + w_ * 0.5f);
    float by2 = clamp01(cy + h_ * 0.5f);

    if (t == 0 && q == 0) {
        out_boxes[b * 4 + 0] = bx1;
        out_boxes[b * 4 + 1] = by1;
        out_boxes[b * 4 + 2] = bx2;
        out_boxes[b * 4 + 3] = by2;
    }

    float ww = fmaxf(bx2 - bx1, 1e-4f);
    float hh = fmaxf(by2 - by1, 1e-4f);
    float diag = sqrtf(ww * ww + hh * hh);
    float margin = fminf(fmaxf(diag * 0.2f, 0.02f), 0.2f);
    float mx1 = clamp01(bx1 - margin);
    float my1 = clamp01(by1 - margin);
    float mx2 = clamp01(bx2 + margin);
    float my2 = clamp01(by2 + margin);

    __syncthreads();

    float asum = 0.0f;
    const int p0 = q * 1024;
    for (int pi = t; pi < 1024; pi += 256) {
        const int p = p0 + pi;
        const int y = p >> 6;
        const int x = p & 63;
        float mv[9];
        #pragma unroll
        for (int ky = 0; ky < 3; ++ky) {
            const int yy = y + ky - 1;
            float gy = (float)((double)yy / 63.0);
            bool yin = (yy >= 0) && (yy < H_) && (gy >= my1) && (gy <= my2);
            #pragma unroll
            for (int kx = 0; kx < 3; ++kx) {
                const int xx = x + kx - 1;
                float gx = (float)((double)xx / 63.0);
                bool xin = (xx >= 0) && (xx < W_) && (gx >= mx1) && (gx <= mx2);
                mv[ky * 3 + kx] = (yin && xin) ? 1.0f : 0.0f;
            }
        }
        float z = b2v;
        #pragma unroll
        for (int oc = 0; oc < 16; ++oc) {
            float hsum = sb1[oc];
            #pragma unroll
            for (int k = 0; k < 9; ++k) hsum = fmaf(mv[k], sw1[oc * 9 + k], hsum);
            z = fmaf(fmaxf(hsum, 0.0f), sw2[oc], z);
        }
        float rm = 1.0f / (1.0f + expf(-z));
        out_rm[b * HW + p] = rm;
        asum += rm;
    }

    #pragma unroll
    for (int off = 32; off > 0; off >>= 1) asum += __shfl_down(asum, off, 64);
    int lane = t & 63, wid = t >> 6;
    if (lane == 0) sred[wid] = asum;
    __syncthreads();
    if (t == 0) ws_part[b * 4 + q] = sred[0] + sred[1] + sred[2] + sred[3];
}

// Kernel B: pointer_feat[b,c] = sum(feat[b,c,:,:] * rm[b,:,:]) / area[b]
// 8 channel rows per block for ILP; rm row read once per iter.
__global__ __launch_bounds__(256) void kern_pf(
    const float* __restrict__ feat, const float* __restrict__ rm,
    const float* __restrict__ ws_part, float* __restrict__ out_pf)
{
    const int blk = blockIdx.x;          // b*32 + g
    const int b = blk >> 5;
    const int c0 = (blk & 31) * PF_RPB;
    __shared__ float sred[4][PF_RPB];

    const size_t row0 = ((size_t)b * C_ + c0) * HW;
    const f32x4* fr = (const f32x4*)(feat + row0);
    const f32x4* r4 = (const f32x4*)(rm + (size_t)b * HW);

    float s[PF_RPB];
    #pragma unroll
    for (int j = 0; j < PF_RPB; ++j) s[j] = 0.0f;

    for (int i = threadIdx.x; i < HW4; i += 256) {
        f32x4 r = r4[i];
        #pragma unroll
        for (int j = 0; j < PF_RPB; ++j) {
            f32x4 f = fr[i + j * HW4];
            s[j] = fmaf(f.x, r.x, fmaf(f.y, r.y, fmaf(f.z, r.z, fmaf(f.w, r.w, s[j]))));
        }
    }

    #pragma unroll
    for (int j = 0; j < PF_RPB; ++j) {
        #pragma unroll
        for (int off = 32; off > 0; off >>= 1) s[j] += __shfl_down(s[j], off, 64);
    }
    int lane = threadIdx.x & 63, wid = threadIdx.x >> 6;
    if (lane == 0) {
        #pragma unroll
        for (int j = 0; j < PF_RPB; ++j) sred[wid][j] = s[j];
    }
    __syncthreads();
    if (threadIdx.x < PF_RPB) {
        int j = threadIdx.x;
        float area = fmaxf(ws_part[b * 4 + 0] + ws_part[b * 4 + 1] +
                           ws_part[b * 4 + 2] + ws_part[b * 4 + 3], 1.0f);
        float tot = sred[0][j] + sred[1][j] + sred[2][j] + sred[3][j];
        out_pf[b * C_ + c0 + j] = tot / area;
    }
}

// Kernel C (fused MLP + guided stream): block = (b, 16-channel group).
// Every block redundantly computes the cg hidden layer + its 16 gates.
// g==0 blocks additionally compute the lf MLP -> guided_lang.
// Then streams: out = feat*(1+0.6*rm)*gate[c], nt stores.
__global__ __launch_bounds__(256) void kern_guided(
    const float* __restrict__ feat, const float* __restrict__ rm,
    const float* __restrict__ pf, const float* __restrict__ lang,
    const float* __restrict__ cg_w1, const float* __restrict__ cg_b1,
    const float* __restrict__ cg_w2, const float* __restrict__ cg_b2,
    const float* __restrict__ lf_w1, const float* __restrict__ lf_b1,
    const float* __restrict__ lf_w2, const float* __restrict__ lf_b2,
    float* __restrict__ out_gl, float* __restrict__ out_gf)
{
    const int blk = blockIdx.x;          // b*16 + g
    const int b = blk >> 4;
    const int g = blk & 15;
    const int c0 = g * GD_RPB;
    const int t = threadIdx.x;

    __shared__ float fus[512];
    __shared__ float hid[256];
    __shared__ float hid_lf[256];
    __shared__ float gates[GD_RPB];

    fus[t]       = pf[b * 256 + t];
    fus[256 + t] = lang[b * 256 + t];
    __syncthreads();

    // layer 1 (cg): hid[t] = relu(dot(w1 row t, fus) + b1[t])
    {
        const f32x4* wv = (const f32x4*)(cg_w1 + (size_t)t * 512);
        const f32x4* fv = (const f32x4*)fus;
        float s = 0.0f;
        #pragma unroll 8
        for (int k = 0; k < 128; ++k) {
            f32x4 f = fv[k], w = wv[k];
            s = fmaf(f.x, w.x, fmaf(f.y, w.y, fmaf(f.z, w.z, fmaf(f.w, w.w, s))));
        }
        hid[t] = fmaxf(s + cg_b1[t], 0.0f);
    }
    __syncthreads();

    // gates for this block's 16 channels (threads 0..15)
    if (t < GD_RPB) {
        const int c = c0 + t;
        const f32x4* wv = (const f32x4*)(cg_w2 + (size_t)c * 256);
        const f32x4* hv = (const f32x4*)hid;
        float s = 0.0f;
        #pragma unroll 8
        for (int k = 0; k < 64; ++k) {
            f32x4 h = hv[k], w = wv[k];
            s = fmaf(h.x, w.x, fmaf(h.y, w.y, fmaf(h.z, w.z, fmaf(h.w, w.w, s))));
        }
        s += cg_b2[c];
        gates[t] = 1.0f + 0.5f / (1.0f + expf(-s));
    }
    // lf hidden layer (only g==0 blocks; block-uniform branch)
    if (g == 0) {
        const f32x4* wv = (const f32x4*)(lf_w1 + (size_t)t * 512);
        const f32x4* fv = (const f32x4*)fus;
        float s = 0.0f;
        #pragma unroll 8
        for (int k = 0; k < 128; ++k) {
            f32x4 f = fv[k], w = wv[k];
            s = fmaf(f.x, w.x, fmaf(f.y, w.y, fmaf(f.z, w.z, fmaf(f.w, w.w, s))));
        }
        hid_lf[t] = fmaxf(s + lf_b1[t], 0.0f);
    }
    __syncthreads();

    if (g == 0) {
        const f32x4* wv = (const f32x4*)(lf_w2 + (size_t)t * 256);
        const f32x4* hv = (const f32x4*)hid_lf;
        float s = 0.0f;
        #pragma unroll 8
        for (int k = 0; k < 64; ++k) {
            f32x4 h = hv[k], w = wv[k];
            s = fmaf(h.x, w.x, fmaf(h.y, w.y, fmaf(h.z, w.z, fmaf(h.w, w.w, s))));
        }
        out_gl[b * 256 + t] = fus[256 + t] + 0.4f * tanhf(s + lf_b2[t]);
    }

    // hoist gates into registers
    float gr[GD_RPB];
    #pragma unroll
    for (int j = 0; j < GD_RPB; ++j) gr[j] = gates[j];

    // stream 16 channel rows
    const size_t row0 = ((size_t)b * C_ + c0) * HW;
    const f32x4* fr = (const f32x4*)(feat + row0);
    f32x4* orow = (f32x4*)(out_gf + row0);
    const f32x4* r4 = (const f32x4*)(rm + (size_t)b * HW);

    for (int i = t; i < HW4; i += 256) {
        f32x4 r = r4[i];
        f32x4 m;
        m.x = 1.0f + 0.6f * r.x;
        m.y = 1.0f + 0.6f * r.y;
        m.z = 1.0f + 0.6f * r.z;
        m.w = 1.0f + 0.6f * r.w;
        #pragma unroll
        for (int j = 0; j < GD_RPB; ++j) {
            f32x4 f = fr[i + j * HW4];
            f32x4 o;
            o.x = f.x * m.x * gr[j];
            o.y = f.y * m.y * gr[j];
            o.z = f.z * m.z * gr[j];
            o.w = f.w * m.w * gr[j];
            __builtin_nontemporal_store(o, &orow[i + j * HW4]);
        }
    }
}

extern "C" void kernel_launch(void* const* d_in, const int* in_sizes, int n_in,
                              void* d_out, int out_size, void* d_ws, size_t ws_size,
                              hipStream_t stream) {
    const float* feat     = (const float*)d_in[0];
    const float* lang     = (const float*)d_in[1];
    const float* xywh     = (const float*)d_in[2];
    const float* conv1_w  = (const float*)d_in[3];
    const float* conv1_b  = (const float*)d_in[4];
    const float* conv2_w  = (const float*)d_in[5];
    const float* conv2_b  = (const float*)d_in[6];
    const float* cg_w1    = (const float*)d_in[7];
    const float* cg_b1    = (const float*)d_in[8];
    const float* cg_w2    = (const float*)d_in[9];
    const float* cg_b2    = (const float*)d_in[10];
    const float* lf_w1    = (const float*)d_in[11];
    const float* lf_b1    = (const float*)d_in[12];
    const float* lf_w2    = (const float*)d_in[13];
    const float* lf_b2    = (const float*)d_in[14];

    float* out = (float*)d_out;
    const size_t N_GF = (size_t)B_ * C_ * HW;    // 33554432
    float* out_gf    = out;
    float* out_gl    = out_gf + N_GF;            // 8192
    float* out_boxes = out_gl + (size_t)B_ * C_; // 128
    float* out_rm    = out_boxes + B_ * 4;       // 131072
    float* out_pf    = out_rm + (size_t)B_ * HW; // 8192

    float* wsf     = (float*)d_ws;
    float* ws_part = wsf;                  // 128 partial area sums

    (void)ws_size; (void)in_sizes; (void)n_in; (void)out_size;

    kern_mask<<<B_ * 4, 256, 0, stream>>>(xywh, conv1_w, conv1_b, conv2_w, conv2_b,
                                          out_boxes, out_rm, ws_part);
    kern_pf<<<B_ * C_ / PF_RPB, 256, 0, stream>>>(feat, out_rm, ws_part, out_pf);
    kern_guided<<<B_ * C_ / GD_RPB, 256, 0, stream>>>(feat, out_rm, out_pf, lang,
                                                      cg_w1, cg_b1, cg_w2, cg_b2,
                                                      lf_w1, lf_b1, lf_w2, lf_b2,
                                                      out_gl, out_gf);
}

// Round 5
// 94.997 us; speedup vs baseline: 1.3009x; 1.3009x over previous
//
#include <hip/hip_runtime.h>
#include <math.h>

#define B_  32
#define C_  256
#define H_  64
#define W_  64
#define HW  (H_*W_)          // 4096
#define HW4 (HW/4)           // 1024
#define RPB 4                // channel rows per block in streaming kernels (grid 2048 = 8 blocks/CU)

typedef float f32x4 __attribute__((ext_vector_type(4)));

__device__ __forceinline__ float clamp01(float v) {
    return fminf(fmaxf(v, 0.0f), 1.0f);
}

// Kernel A: 4 blocks per batch. boxes -> analytic mask -> conv1(3x3,16)+relu
// -> conv2(1x1)+sigmoid -> refined_mask out + partial area to ws.
__global__ __launch_bounds__(256) void kern_mask(
    const float* __restrict__ xywh,
    const float* __restrict__ conv1_w, const float* __restrict__ conv1_b,
    const float* __restrict__ conv2_w, const float* __restrict__ conv2_b,
    float* __restrict__ out_boxes, float* __restrict__ out_rm,
    float* __restrict__ ws_part)
{
    const int b = blockIdx.x >> 2;
    const int q = blockIdx.x & 3;
    const int t = threadIdx.x;

    __shared__ float sw1[16 * 9];
    __shared__ float sb1[16];
    __shared__ float sw2[16];
    __shared__ float sred[4];

    if (t < 144)                 sw1[t]       = conv1_w[t];
    else if (t < 160)            sb1[t - 144] = conv1_b[t - 144];
    else if (t < 176)            sw2[t - 160] = conv2_w[t - 160];
    const float b2v = conv2_b[0];

    const float xc = xywh[b * 4 + 0];
    const float yc = xywh[b * 4 + 1];
    const float bw = xywh[b * 4 + 2];
    const float bh = xywh[b * 4 + 3];

    float x1 = clamp01(xc - bw * 0.5f);
    float y1 = clamp01(yc - bh * 0.5f);
    float x2 = clamp01(xc + bw * 0.5f);
    float y2 = clamp01(yc + bh * 0.5f);
    float xl = fminf(x1, x2), xh = fmaxf(x1, x2);
    float yl = fminf(y1, y2), yh = fmaxf(y1, y2);
    float w_ = fmaxf(xh - xl, 1e-6f);
    float h_ = fmaxf(yh - yl, 1e-6f);
    float cx = (xh + xl) * 0.5f, cy = (yh + yl) * 0.5f;
    float bx1 = clamp01(cx - w_ * 0.5f);
    float by1 = clamp01(cy - h_ * 0.5f);
    float bx2 = clamp01(cx + w_ * 0.5f);
    float by2 = clamp01(cy + h_ * 0.5f);

    if (t == 0 && q == 0) {
        out_boxes[b * 4 + 0] = bx1;
        out_boxes[b * 4 + 1] = by1;
        out_boxes[b * 4 + 2] = bx2;
        out_boxes[b * 4 + 3] = by2;
    }

    float ww = fmaxf(bx2 - bx1, 1e-4f);
    float hh = fmaxf(by2 - by1, 1e-4f);
    float diag = sqrtf(ww * ww + hh * hh);
    float margin = fminf(fmaxf(diag * 0.2f, 0.02f), 0.2f);
    float mx1 = clamp01(bx1 - margin);
    float my1 = clamp01(by1 - margin);
    float mx2 = clamp01(bx2 + margin);
    float my2 = clamp01(by2 + margin);

    __syncthreads();

    float asum = 0.0f;
    const int p0 = q * 1024;
    for (int pi = t; pi < 1024; pi += 256) {
        const int p = p0 + pi;
        const int y = p >> 6;
        const int x = p & 63;
        float mv[9];
        #pragma unroll
        for (int ky = 0; ky < 3; ++ky) {
            const int yy = y + ky - 1;
            float gy = (float)((double)yy / 63.0);
            bool yin = (yy >= 0) && (yy < H_) && (gy >= my1) && (gy <= my2);
            #pragma unroll
            for (int kx = 0; kx < 3; ++kx) {
                const int xx = x + kx - 1;
                float gx = (float)((double)xx / 63.0);
                bool xin = (xx >= 0) && (xx < W_) && (gx >= mx1) && (gx <= mx2);
                mv[ky * 3 + kx] = (yin && xin) ? 1.0f : 0.0f;
            }
        }
        float z = b2v;
        #pragma unroll
        for (int oc = 0; oc < 16; ++oc) {
            float hsum = sb1[oc];
            #pragma unroll
            for (int k = 0; k < 9; ++k) hsum = fmaf(mv[k], sw1[oc * 9 + k], hsum);
            z = fmaf(fmaxf(hsum, 0.0f), sw2[oc], z);
        }
        float rm = 1.0f / (1.0f + expf(-z));
        out_rm[b * HW + p] = rm;
        asum += rm;
    }

    #pragma unroll
    for (int off = 32; off > 0; off >>= 1) asum += __shfl_down(asum, off, 64);
    int lane = t & 63, wid = t >> 6;
    if (lane == 0) sred[wid] = asum;
    __syncthreads();
    if (t == 0) ws_part[b * 4 + q] = sred[0] + sred[1] + sred[2] + sred[3];
}

// Kernel B: pointer_feat[b,c] = sum(feat[b,c,:,:] * rm[b,:,:]) / area[b]
// 4 channel rows per block; 2048 blocks -> 8 blocks/CU, full TLP.
__global__ __launch_bounds__(256) void kern_pf(
    const float* __restrict__ feat, const float* __restrict__ rm,
    const float* __restrict__ ws_part, float* __restrict__ out_pf)
{
    const int blk = blockIdx.x;          // b*64 + g
    const int b = blk >> 6;
    const int c0 = (blk & 63) * RPB;
    __shared__ f32x4 sred[4];

    const size_t row0 = ((size_t)b * C_ + c0) * HW;
    const f32x4* fr = (const f32x4*)(feat + row0);
    const f32x4* r4 = (const f32x4*)(rm + (size_t)b * HW);

    float s0 = 0.f, s1 = 0.f, s2 = 0.f, s3 = 0.f;
    for (int i = threadIdx.x; i < HW4; i += 256) {
        f32x4 r = r4[i];
        f32x4 f0 = fr[i];
        f32x4 f1 = fr[i + HW4];
        f32x4 f2 = fr[i + 2 * HW4];
        f32x4 f3 = fr[i + 3 * HW4];
        s0 = fmaf(f0.x, r.x, fmaf(f0.y, r.y, fmaf(f0.z, r.z, fmaf(f0.w, r.w, s0))));
        s1 = fmaf(f1.x, r.x, fmaf(f1.y, r.y, fmaf(f1.z, r.z, fmaf(f1.w, r.w, s1))));
        s2 = fmaf(f2.x, r.x, fmaf(f2.y, r.y, fmaf(f2.z, r.z, fmaf(f2.w, r.w, s2))));
        s3 = fmaf(f3.x, r.x, fmaf(f3.y, r.y, fmaf(f3.z, r.z, fmaf(f3.w, r.w, s3))));
    }

    #pragma unroll
    for (int off = 32; off > 0; off >>= 1) {
        s0 += __shfl_down(s0, off, 64);
        s1 += __shfl_down(s1, off, 64);
        s2 += __shfl_down(s2, off, 64);
        s3 += __shfl_down(s3, off, 64);
    }
    int lane = threadIdx.x & 63, wid = threadIdx.x >> 6;
    if (lane == 0) { f32x4 v; v.x = s0; v.y = s1; v.z = s2; v.w = s3; sred[wid] = v; }
    __syncthreads();
    if (threadIdx.x == 0) {
        float area = fmaxf(ws_part[b * 4 + 0] + ws_part[b * 4 + 1] +
                           ws_part[b * 4 + 2] + ws_part[b * 4 + 3], 1.0f);
        float inv = 1.0f / area;
        f32x4 t0 = sred[0], t1 = sred[1], t2 = sred[2], t3 = sred[3];
        out_pf[b * C_ + c0 + 0] = (t0.x + t1.x + t2.x + t3.x) * inv;
        out_pf[b * C_ + c0 + 1] = (t0.y + t1.y + t2.y + t3.y) * inv;
        out_pf[b * C_ + c0 + 2] = (t0.z + t1.z + t2.z + t3.z) * inv;
        out_pf[b * C_ + c0 + 3] = (t0.w + t1.w + t2.w + t3.w) * inv;
    }
}

// Kernel C: fused 2-layer MLP. 2 blocks per batch: which=0 -> ch_gate,
// which=1 -> guided_lang. Hidden layer lives in LDS.
__global__ __launch_bounds__(256) void kern_mlp(
    const float* __restrict__ pf, const float* __restrict__ lang,
    const float* __restrict__ cg_w1, const float* __restrict__ cg_b1,
    const float* __restrict__ cg_w2, const float* __restrict__ cg_b2,
    const float* __restrict__ lf_w1, const float* __restrict__ lf_b1,
    const float* __restrict__ lf_w2, const float* __restrict__ lf_b2,
    float* __restrict__ ws_cg, float* __restrict__ out_gl)
{
    const int b = blockIdx.x >> 1;
    const int which = blockIdx.x & 1;
    const int t = threadIdx.x;
    __shared__ float fus[512];
    __shared__ float hid[256];

    fus[t]       = pf[b * 256 + t];
    fus[256 + t] = lang[b * 256 + t];

    const float* w1 = which ? lf_w1 : cg_w1;
    const float* b1 = which ? lf_b1 : cg_b1;
    const float* w2 = which ? lf_w2 : cg_w2;
    const float* b2 = which ? lf_b2 : cg_b2;
    __syncthreads();

    const f32x4* wv = (const f32x4*)(w1 + (size_t)t * 512);
    const f32x4* fv = (const f32x4*)fus;
    float s = 0.0f;
    #pragma unroll 4
    for (int k = 0; k < 128; ++k) {
        f32x4 f = fv[k], w = wv[k];
        s = fmaf(f.x, w.x, fmaf(f.y, w.y, fmaf(f.z, w.z, fmaf(f.w, w.w, s))));
    }
    hid[t] = fmaxf(s + b1[t], 0.0f);
    __syncthreads();

    const f32x4* w2v = (const f32x4*)(w2 + (size_t)t * 256);
    const f32x4* hv = (const f32x4*)hid;
    float s2 = 0.0f;
    #pragma unroll 4
    for (int k = 0; k < 64; ++k) {
        f32x4 h = hv[k], w = w2v[k];
        s2 = fmaf(h.x, w.x, fmaf(h.y, w.y, fmaf(h.z, w.z, fmaf(h.w, w.w, s2))));
    }
    s2 += b2[t];
    if (which == 0) {
        ws_cg[b * 256 + t] = 1.0f + 0.5f / (1.0f + expf(-s2));   // pre-biased gate
    } else {
        out_gl[b * 256 + t] = fus[256 + t] + 0.4f * tanhf(s2);
    }
}

// Kernel D: guided_feat = feat * (1 + 0.6*rm) * gate[c].
// 4 channel rows per block (2048 blocks = 8/CU, 32 waves/CU); plain feat loads
// (harvest L3 leftovers from kern_pf), nt stores (don't evict feat).
__global__ __launch_bounds__(256) void kern_guided(
    const float* __restrict__ feat, const float* __restrict__ rm,
    const float* __restrict__ ws_cg, float* __restrict__ out_gf)
{
    const int blk = blockIdx.x;          // b*64 + g
    const int b = blk >> 6;
    const int c0 = (blk & 63) * RPB;
    const float g0 = ws_cg[b * C_ + c0 + 0];
    const float g1 = ws_cg[b * C_ + c0 + 1];
    const float g2 = ws_cg[b * C_ + c0 + 2];
    const float g3 = ws_cg[b * C_ + c0 + 3];

    const size_t row0 = ((size_t)b * C_ + c0) * HW;
    const f32x4* fr = (const f32x4*)(feat + row0);
    f32x4* orow = (f32x4*)(out_gf + row0);
    const f32x4* r4 = (const f32x4*)(rm + (size_t)b * HW);

    for (int i = threadIdx.x; i < HW4; i += 256) {
        f32x4 r = r4[i];
        f32x4 m;
        m.x = 1.0f + 0.6f * r.x;
        m.y = 1.0f + 0.6f * r.y;
        m.z = 1.0f + 0.6f * r.z;
        m.w = 1.0f + 0.6f * r.w;
        f32x4 f0 = fr[i];
        f32x4 f1 = fr[i + HW4];
        f32x4 f2 = fr[i + 2 * HW4];
        f32x4 f3 = fr[i + 3 * HW4];
        f32x4 o0, o1, o2, o3;
        o0.x = f0.x * m.x * g0; o0.y = f0.y * m.y * g0;
        o0.z = f0.z * m.z * g0; o0.w = f0.w * m.w * g0;
        o1.x = f1.x * m.x * g1; o1.y = f1.y * m.y * g1;
        o1.z = f1.z * m.z * g1; o1.w = f1.w * m.w * g1;
        o2.x = f2.x * m.x * g2; o2.y = f2.y * m.y * g2;
        o2.z = f2.z * m.z * g2; o2.w = f2.w * m.w * g2;
        o3.x = f3.x * m.x * g3; o3.y = f3.y * m.y * g3;
        o3.z = f3.z * m.z * g3; o3.w = f3.w * m.w * g3;
        __builtin_nontemporal_store(o0, &orow[i]);
        __builtin_nontemporal_store(o1, &orow[i + HW4]);
        __builtin_nontemporal_store(o2, &orow[i + 2 * HW4]);
        __builtin_nontemporal_store(o3, &orow[i + 3 * HW4]);
    }
}

extern "C" void kernel_launch(void* const* d_in, const int* in_sizes, int n_in,
                              void* d_out, int out_size, void* d_ws, size_t ws_size,
                              hipStream_t stream) {
    const float* feat     = (const float*)d_in[0];
    const float* lang     = (const float*)d_in[1];
    const float* xywh     = (const float*)d_in[2];
    const float* conv1_w  = (const float*)d_in[3];
    const float* conv1_b  = (const float*)d_in[4];
    const float* conv2_w  = (const float*)d_in[5];
    const float* conv2_b  = (const float*)d_in[6];
    const float* cg_w1    = (const float*)d_in[7];
    const float* cg_b1    = (const float*)d_in[8];
    const float* cg_w2    = (const float*)d_in[9];
    const float* cg_b2    = (const float*)d_in[10];
    const float* lf_w1    = (const float*)d_in[11];
    const float* lf_b1    = (const float*)d_in[12];
    const float* lf_w2    = (const float*)d_in[13];
    const float* lf_b2    = (const float*)d_in[14];

    float* out = (float*)d_out;
    const size_t N_GF = (size_t)B_ * C_ * HW;    // 33554432
    float* out_gf    = out;
    float* out_gl    = out_gf + N_GF;            // 8192
    float* out_boxes = out_gl + (size_t)B_ * C_; // 128
    float* out_rm    = out_boxes + B_ * 4;       // 131072
    float* out_pf    = out_rm + (size_t)B_ * HW; // 8192

    float* wsf     = (float*)d_ws;
    float* ws_part = wsf;                  // 128 partial area sums
    float* ws_cg   = wsf + 128;            // 8192 pre-biased gates

    (void)ws_size; (void)in_sizes; (void)n_in; (void)out_size;

    kern_mask<<<B_ * 4, 256, 0, stream>>>(xywh, conv1_w, conv1_b, conv2_w, conv2_b,
                                          out_boxes, out_rm, ws_part);
    kern_pf<<<B_ * C_ / RPB, 256, 0, stream>>>(feat, out_rm, ws_part, out_pf);
    kern_mlp<<<B_ * 2, 256, 0, stream>>>(out_pf, lang,
                                         cg_w1, cg_b1, cg_w2, cg_b2,
                                         lf_w1, lf_b1, lf_w2, lf_b2,
                                         ws_cg, out_gl);
    kern_guided<<<B_ * C_ / RPB, 256, 0, stream>>>(feat, out_rm, ws_cg, out_gf);
}